// Round 9
// baseline (927.127 us; speedup 1.0000x reference)
//
#include <hip/hip_runtime.h>
#include <math.h>

// Problem constants
#define kB 32768
#define kD 2048
#define kH 1024
#define kL 384
#define kP 192
#define kC 10
#define kNP 2
#define kND 2
#define kNCAT 768
#define kTAU 0.1f
#define kEPS 1e-5f
#define NPART 512                 // stats partials: 2 wave-rows * 256 row-panels
#define SCALE 64.0f               // operand pre-scale (keeps f16 lo-plane normal)
#define INV_SC2 (1.0f / 4096.0f)  // GEMM outputs carry SCALE^2

typedef _Float16 f16x8 __attribute__((ext_vector_type(8)));
typedef float f32x16 __attribute__((ext_vector_type(16)));

// async global->LDS, 16B per lane (linear LDS dest: base + lane*16)
__device__ __forceinline__ void gll16(const unsigned short* g, unsigned short* l)
{
    __builtin_amdgcn_global_load_lds(
        (const __attribute__((address_space(1))) unsigned int*)g,
        (__attribute__((address_space(3))) unsigned int*)l, 16, 0, 0);
}

// Bank key (r5-verified: SQ_LDS_BANK_CONFLICT == 0 for writes and 16x16 reads):
// bit0->bit0, bit1->bit2, bit2->bit1. Any aligned-8-row group maps a fixed
// logical chunk to 8 distinct stored slots -> conflict-free consecutive-8 reads.
__device__ __host__ __forceinline__ int wkey(int r)
{
    return (r & 1) | ((r & 2) << 1) | ((r & 4) >> 1);
}

// ---------------------------------------------------------------------------
// split_pack: fp32 [rows][K] -> packed f16 hi/lo planes, pre-swizzled.
// One thread per 32-k block: 128B coalesced read, 128B window write.
// Per 32-k block: 8 chunks(16B): logical 0..3 hi, 4..7 lo; stored chunk =
// logical ^ wkey(row&7). Values scaled by 64.
// ---------------------------------------------------------------------------
__global__ __launch_bounds__(256)
void split_pack(const float* __restrict__ in, unsigned short* __restrict__ out,
                int lognkb, int total)
{
    const int gid = blockIdx.x * 256 + threadIdx.x;
    if (gid >= total) return;
    const int nkb = 1 << lognkb;
    const int row = gid >> lognkb;
    const int kb  = gid & (nkb - 1);
    const float* src = in + ((size_t)row << (lognkb + 5)) + kb * 32;
    unsigned short* dst = out + ((size_t)row << (lognkb + 6)) + kb * 64;
    const int s = wkey(row & 7);
#pragma unroll
    for (int h = 0; h < 4; ++h) {
        const float4 a = *(const float4*)&src[h * 8];
        const float4 b = *(const float4*)&src[h * 8 + 4];
        const float v[8] = {a.x, a.y, a.z, a.w, b.x, b.y, b.z, b.w};
        f16x8 hi, lo;
#pragma unroll
        for (int i = 0; i < 8; ++i) {
            const float x = v[i] * SCALE;
            const _Float16 hh = (_Float16)x;
            hi[i] = hh;
            lo[i] = (_Float16)(x - (float)hh);
        }
        *(f16x8*)&dst[((h ^ s) << 3)]       = hi;
        *(f16x8*)&dst[(((h ^ 4) ^ s) << 3)] = lo;
    }
}

// ---------------------------------------------------------------------------
// split_bn: Z1' (4096x-scaled fp32 [32768][1024]) -> fused BN+ReLU (scale/
// shift embed de-scale and the x64 feature pre-scale) -> packed f16 planes.
// ---------------------------------------------------------------------------
__global__ __launch_bounds__(256)
void split_bn(const float* __restrict__ Z, const float* __restrict__ scl,
              const float* __restrict__ shf, unsigned short* __restrict__ out)
{
    const int gid = blockIdx.x * 256 + threadIdx.x;   // kB*32 threads
    const int row = gid >> 5, kb = gid & 31;
    const float* src = Z + (size_t)row * kH + kb * 32;
    unsigned short* dst = out + (size_t)row * 2048 + kb * 64;
    const int s = wkey(row & 7);
#pragma unroll
    for (int h = 0; h < 4; ++h) {
        const float4 a  = *(const float4*)&src[h * 8];
        const float4 b  = *(const float4*)&src[h * 8 + 4];
        const float4 c0 = *(const float4*)&scl[kb * 32 + h * 8];
        const float4 c1 = *(const float4*)&scl[kb * 32 + h * 8 + 4];
        const float4 d0 = *(const float4*)&shf[kb * 32 + h * 8];
        const float4 d1 = *(const float4*)&shf[kb * 32 + h * 8 + 4];
        const float v[8] = {
            fmaxf(fmaf(a.x, c0.x, d0.x), 0.f), fmaxf(fmaf(a.y, c0.y, d0.y), 0.f),
            fmaxf(fmaf(a.z, c0.z, d0.z), 0.f), fmaxf(fmaf(a.w, c0.w, d0.w), 0.f),
            fmaxf(fmaf(b.x, c1.x, d1.x), 0.f), fmaxf(fmaf(b.y, c1.y, d1.y), 0.f),
            fmaxf(fmaf(b.z, c1.z, d1.z), 0.f), fmaxf(fmaf(b.w, c1.w, d1.w), 0.f)};
        f16x8 hi, lo;
#pragma unroll
        for (int i = 0; i < 8; ++i) {
            const _Float16 hh = (_Float16)v[i];
            hi[i] = hh;
            lo[i] = (_Float16)(v[i] - (float)hh);
        }
        *(f16x8*)&dst[((h ^ s) << 3)]       = hi;
        *(f16x8*)&dst[(((h ^ 4) ^ s) << 3)] = lo;
    }
}

// ---------------------------------------------------------------------------
// Pure-DMA split-f16 MFMA GEMM (r2 structure, r8-falsified staging removed):
// 128x128 tile, 4 waves (2x2 of 64x64), BK=32, single-buffered 32KB LDS,
// both operands pre-packed + global_load_lds, __syncthreads() pair per step.
// v_mfma_f32_32x32x16_f16 (2495 TF ubench vs 2075 for 16x16): per wave 2x2
// frags of 32x32, 24 MFMA/step. Fragment mappings r4-HW-verified.
// Epilogue: C store + fused column partial stats.
// ---------------------------------------------------------------------------
template<int KDIM>
__global__ __launch_bounds__(256, 3)
void gemm_dma(const unsigned short* __restrict__ Apk,
              const unsigned short* __restrict__ Bpk,
              float* __restrict__ C, const int N, const int gridX,
              float* __restrict__ psum, float* __restrict__ psumsq, const int statN)
{
    constexpr int NKB = KDIM / 32;
    __shared__ __align__(16) unsigned short As_[128 * 64];
    __shared__ __align__(16) unsigned short Bs_[128 * 64];

    const int t = threadIdx.x;
    const int lane = t & 63;
    const int w = t >> 6;                // 0..3
    const int wr = w >> 1, wc = w & 1;   // 2x2 wave grid; per-wave 64x64
    const int l31 = lane & 31, kg = lane >> 5;
    const int key = wkey(l31 & 7);

    // XCD-chunked swizzle (bijective: nwg % 8 == 0)
    const int nwg = gridDim.x;
    const int chunk = nwg >> 3;
    const int bid = blockIdx.x;
    const int logical = (bid & 7) * chunk + (bid >> 3);
    const int bx = logical % gridX, by = logical / gridX;
    const int m0 = by * 128, n0 = bx * 128;

    // staging descriptors: per wave 4 groups; Q = chunk id in tile
    const size_t stride = (size_t)NKB * 64;
    const unsigned short* aG[4];
    const unsigned short* bG[4];
    int loff[4];
#pragma unroll
    for (int it = 0; it < 4; ++it) {
        const int Q = (w * 4 + it) * 64 + lane;
        const int row = Q >> 3, c = Q & 7;
        aG[it] = Apk + (size_t)(m0 + row) * stride + c * 8;
        bG[it] = Bpk + (size_t)(n0 + row) * stride + c * 8;
        loff[it] = (w * 4 + it) * 512;
    }

    f32x16 acc[2][2];
#pragma unroll
    for (int mi = 0; mi < 2; ++mi)
#pragma unroll
        for (int ni = 0; ni < 2; ++ni)
#pragma unroll
            for (int r = 0; r < 16; ++r) acc[mi][ni][r] = 0.f;

    for (int kb = 0; kb < NKB; ++kb) {
        const size_t ko = (size_t)kb * 64;
#pragma unroll
        for (int it = 0; it < 4; ++it) {
            gll16(aG[it] + ko, &As_[loff[it]]);
            gll16(bG[it] + ko, &Bs_[loff[it]]);
        }
        __syncthreads();   // drains vmcnt: LDS tiles ready

#pragma unroll
        for (int ks = 0; ks < 2; ++ks) {
            const int ch = (ks * 2 + kg) ^ key;   // stored chunk of hi slice
            const int cl = ch ^ 4;                // lo slice
            f16x8 bh[2], bl[2];
#pragma unroll
            for (int ni = 0; ni < 2; ++ni) {
                const unsigned short* bb = &Bs_[(wc * 64 + ni * 32 + l31) * 64];
                bh[ni] = *(const f16x8*)&bb[ch * 8];
                bl[ni] = *(const f16x8*)&bb[cl * 8];
            }
#pragma unroll
            for (int mi = 0; mi < 2; ++mi) {
                const unsigned short* ab = &As_[(wr * 64 + mi * 32 + l31) * 64];
                const f16x8 ah = *(const f16x8*)&ab[ch * 8];
                const f16x8 al = *(const f16x8*)&ab[cl * 8];
#pragma unroll
                for (int ni = 0; ni < 2; ++ni) {
                    acc[mi][ni] = __builtin_amdgcn_mfma_f32_32x32x16_f16(ah, bh[ni], acc[mi][ni], 0, 0, 0);
                    acc[mi][ni] = __builtin_amdgcn_mfma_f32_32x32x16_f16(ah, bl[ni], acc[mi][ni], 0, 0, 0);
                    acc[mi][ni] = __builtin_amdgcn_mfma_f32_32x32x16_f16(al, bh[ni], acc[mi][ni], 0, 0, 0);
                }
            }
        }
        __syncthreads();   // all reads done before next DMA overwrite
    }

    // C store (32x32 C/D layout, r4-verified:
    // col = lane&31, row = (r&3) + 8*(r>>2) + 4*(lane>>5))
#pragma unroll
    for (int mi = 0; mi < 2; ++mi)
#pragma unroll
        for (int ni = 0; ni < 2; ++ni) {
            const int colg = n0 + wc * 64 + ni * 32 + l31;
#pragma unroll
            for (int r = 0; r < 16; ++r) {
                const int row = m0 + wr * 64 + mi * 32 + (r & 3) + 8 * (r >> 2) + 4 * kg;
                C[(size_t)row * N + colg] = acc[mi][ni][r];
            }
        }

    // fused column partial stats over this wave's 64 rows
#pragma unroll
    for (int ni = 0; ni < 2; ++ni) {
        float s = 0.f, sq = 0.f;
#pragma unroll
        for (int mi = 0; mi < 2; ++mi)
#pragma unroll
            for (int r = 0; r < 16; ++r) {
                const float v = acc[mi][ni][r];
                s += v;
                sq = fmaf(v, v, sq);
            }
        s  += __shfl_xor(s, 32);
        sq += __shfl_xor(sq, 32);
        const int col = n0 + wc * 64 + ni * 32 + l31;
        if (lane < 32 && col < statN) {
            psum[(size_t)(by * 2 + wr) * statN + col]   = s;
            psumsq[(size_t)(by * 2 + wr) * statN + col] = sq;
        }
    }
}

// ---------------------------------------------------------------------------
// finalize: input partials of Z' = Z/inv_sc; output scale/shift s.t.
// Z'*scale + shift == outsc * (BN(Z)*g + be)
// ---------------------------------------------------------------------------
__global__ __launch_bounds__(256)
void colstat_finalize(const float* __restrict__ psum, const float* __restrict__ psumsq,
                      int ncols, const float* __restrict__ g, const float* __restrict__ be,
                      float* __restrict__ scale, float* __restrict__ shift,
                      float inv_sc, float outsc)
{
    const int c = blockIdx.x * 256 + threadIdx.x;
    if (c >= ncols) return;
    float s = 0.f, sq = 0.f;
    for (int i = 0; i < NPART; ++i) {
        s  += psum[(size_t)i * ncols + c];
        sq += psumsq[(size_t)i * ncols + c];
    }
    const float mup = s * (1.f / kB);
    const float var = (sq * (1.f / kB) - mup * mup) * inv_sc * inv_sc;
    const float scl = outsc * g[c] * rsqrtf(var + kEPS) * inv_sc;
    scale[c] = scl;
    shift[c] = fmaf(-mup, scl, outsc * be[c]);
}

// ---------------------------------------------------------------------------
// Tail: per-row BN2+ReLU -> dom, sw, gumbel routing, selected expert.
// ---------------------------------------------------------------------------
__global__ __launch_bounds__(256)
void tail_kernel(const float* __restrict__ Z2,
                 const float* __restrict__ scale2, const float* __restrict__ shift2,
                 const float* __restrict__ W_dfc, const float* __restrict__ b_dfc,
                 const float* __restrict__ W_sw, const float* __restrict__ b_sw,
                 const float* __restrict__ b1, const float* __restrict__ W2,
                 const float* __restrict__ b2, const float* __restrict__ noise,
                 float* __restrict__ out)
{
    __shared__ float sWdfc[kND * kL];
    __shared__ float sWsw[kNP * kL];
    __shared__ float sW2[kNP * kC * kP];
    __shared__ float sb1[kNP * kP];
    __shared__ float sScale[kL];
    __shared__ float sShift[kL];
    const int t = threadIdx.x;
    for (int i = t; i < kND * kL; i += 256) sWdfc[i] = W_dfc[i];
    for (int i = t; i < kNP * kL; i += 256) sWsw[i] = W_sw[i];
    for (int i = t; i < kNP * kC * kP; i += 256) sW2[i] = W2[i];
    for (int i = t; i < kNP * kP; i += 256) sb1[i] = b1[i];
    for (int i = t; i < kL; i += 256) { sScale[i] = scale2[i]; sShift[i] = shift2[i]; }
    __syncthreads();

    const int lane = t & 63;
    const int b = blockIdx.x * 4 + (t >> 6);
    const float* z = Z2 + (size_t)b * kNCAT;

    float d0 = 0.f, d1 = 0.f, s0 = 0.f, s1 = 0.f;
#pragma unroll
    for (int j = 0; j < 6; ++j) {
        const int k = lane + j * 64;
        const float dp = fmaxf(fmaf(z[k], sScale[k], sShift[k]), 0.f);
        d0 = fmaf(dp, sWdfc[k],      d0);
        d1 = fmaf(dp, sWdfc[kL + k], d1);
        s0 = fmaf(dp, sWsw[k],       s0);
        s1 = fmaf(dp, sWsw[kL + k],  s1);
    }
#pragma unroll
    for (int off = 32; off; off >>= 1) {
        d0 += __shfl_xor(d0, off);
        d1 += __shfl_xor(d1, off);
        s0 += __shfl_xor(s0, off);
        s1 += __shfl_xor(s1, off);
    }
    d0 += b_dfc[0];
    d1 += b_dfc[1];

    const float sw0 = fmaxf(s0 + b_sw[0], 0.f);
    const float sw1 = fmaxf(s1 + b_sw[1], 0.f);
    const float l0 = (sw0 + noise[(size_t)b * 2 + 0]) * (1.f / kTAU);
    const float l1 = (sw1 + noise[(size_t)b * 2 + 1]) * (1.f / kTAU);
    const float mx = fmaxf(l0, l1);
    const float e0 = expf(l0 - mx), e1 = expf(l1 - mx);
    const float inv = 1.f / (e0 + e1);
    const float sgum = e0 * inv + e1 * inv;
    const int idx = (l1 > l0) ? 1 : 0;

    const float* zh = z + kL + idx * kP;
    const float h0 = fmaxf(fmaf(zh[lane],       INV_SC2, sb1[idx * kP + lane]),       0.f);
    const float h1 = fmaxf(fmaf(zh[lane + 64],  INV_SC2, sb1[idx * kP + lane + 64]),  0.f);
    const float h2 = fmaxf(fmaf(zh[lane + 128], INV_SC2, sb1[idx * kP + lane + 128]), 0.f);

    float* cop  = out;
    float* dom  = out + (size_t)kB * kC;
    float* idxo = dom + (size_t)kB * kND;

#pragma unroll
    for (int c = 0; c < kC; ++c) {
        const float* wv = &sW2[(idx * kC + c) * kP];
        float oc = h0 * wv[lane] + h1 * wv[lane + 64] + h2 * wv[lane + 128];
#pragma unroll
        for (int off = 32; off; off >>= 1) oc += __shfl_xor(oc, off);
        if (lane == c) cop[(size_t)b * kC + c] = (oc + b2[idx * kC + c]) * sgum;
    }
    if (lane == 0) {
        dom[(size_t)b * 2 + 0] = d0;
        dom[(size_t)b * 2 + 1] = d1;
        idxo[b] = (float)idx;
    }
}

// ---------------------------------------------------------------------------
extern "C" void kernel_launch(void* const* d_in, const int* in_sizes, int n_in,
                              void* d_out, int out_size, void* d_ws, size_t ws_size,
                              hipStream_t stream)
{
    const float* x       = (const float*)d_in[0];
    const float* W_pre   = (const float*)d_in[1];
    // d_in[2] b_pre: cancels exactly through BatchNorm
    const float* g_pre   = (const float*)d_in[3];
    const float* be_pre  = (const float*)d_in[4];
    const float* W_disc  = (const float*)d_in[5];
    // d_in[6] b_disc: cancels through BatchNorm
    const float* g_disc  = (const float*)d_in[7];
    const float* be_disc = (const float*)d_in[8];
    const float* W_dfc   = (const float*)d_in[9];
    const float* b_dfc   = (const float*)d_in[10];
    const float* W_sw    = (const float*)d_in[11];
    const float* b_sw    = (const float*)d_in[12];
    const float* W1      = (const float*)d_in[13];
    const float* b1      = (const float*)d_in[14];
    const float* W2      = (const float*)d_in[15];
    const float* b2      = (const float*)d_in[16];
    const float* noise   = (const float*)d_in[17];

    // workspace layout (xs region reused: Fs + Z2 after gemm1 consumed xs)
    char* wsb = (char*)d_ws;
    const size_t xs_bytes  = (size_t)kB * (2 * kD) * 2;      // 268.4 MB
    const size_t wps_bytes = (size_t)kH * (2 * kD) * 2;      // 8.39 MB
    const size_t ws2_bytes = (size_t)kNCAT * (2 * kH) * 2;   // 3.15 MB
    unsigned short* xs  = (unsigned short*)wsb;
    unsigned short* Fs  = xs;                                         // [32768][2048] shorts
    float* Z2 = (float*)(wsb + (size_t)kB * (2 * kH) * 2);            // after Fs in xs region
    unsigned short* Wps = (unsigned short*)(wsb + xs_bytes);
    unsigned short* Ws2 = (unsigned short*)(wsb + xs_bytes + wps_bytes);
    float* Z1 = (float*)(wsb + xs_bytes + wps_bytes + ws2_bytes);
    float* psum1  = Z1 + (size_t)kB * kH;
    float* psq1   = psum1 + (size_t)NPART * kH;
    float* psum2  = psq1 + (size_t)NPART * kH;
    float* psq2   = psum2 + (size_t)NPART * kL;
    float* scale1 = psq2 + (size_t)NPART * kL;
    float* shift1 = scale1 + kH;
    float* scale2 = shift1 + kH;
    float* shift2 = scale2 + kL;
    float* out    = (float*)d_out;

    // 1) pack x (x64) and weights
    split_pack<<<dim3(kB * 64 / 256), 256, 0, stream>>>(x, xs, 6, kB * 64);
    split_pack<<<dim3(kH * 64 / 256), 256, 0, stream>>>(W_pre, Wps, 6, kH * 64);
    split_pack<<<dim3(kL * 32 / 256), 256, 0, stream>>>(W_disc, Ws2, 5, kL * 32);
    split_pack<<<dim3(kNP * kP * 32 / 256), 256, 0, stream>>>(
        W1, Ws2 + (size_t)kL * (2 * kH), 5, kNP * kP * 32);
    // 2) Z1' = 4096 * (x @ W_pre.T), pure-DMA GEMM + fused column stats
    gemm_dma<kD><<<dim3(8 * 256), 256, 0, stream>>>(
        xs, Wps, Z1, kH, 8, psum1, psq1, kH);
    // 3) BN1 finalize (outsc=64 folds the feature split pre-scale)
    colstat_finalize<<<dim3(kH / 256), 256, 0, stream>>>(psum1, psq1, kH, g_pre, be_pre,
                                                         scale1, shift1, INV_SC2, SCALE);
    // 4) Fs = pack(64*relu(BN(Z1)))   [overwrites xs region]
    split_bn<<<dim3(kB * 32 / 256), 256, 0, stream>>>(Z1, scale1, shift1, Fs);
    // 5) Z2' = 4096 * (feature @ [W_disc;W1].T) + fused stats (disc cols)
    gemm_dma<kH><<<dim3(6 * 256), 256, 0, stream>>>(
        Fs, Ws2, Z2, kNCAT, 6, psum2, psq2, kL);
    // 6) BN2 finalize (outsc=1)
    colstat_finalize<<<dim3((kL + 255) / 256), 256, 0, stream>>>(psum2, psq2, kL, g_disc, be_disc,
                                                                 scale2, shift2, INV_SC2, 1.0f);
    // 7) routing + experts + outputs
    tail_kernel<<<dim3(kB / 4), 256, 0, stream>>>(Z2, scale2, shift2, W_dfc, b_dfc,
                                                  W_sw, b_sw, b1, W2, b2, noise, out);
}